// Round 1
// baseline (184.387 us; speedup 1.0000x reference)
//
#include <hip/hip_runtime.h>

// MoE top-2 of 3x3 SAME convs via bf16 MFMA implicit GEMM.
//
// R7: FUSE the transpose into the main kernel; delete the xpose prep and the
// xT buffer entirely.
//  - Each block builds its own 6-row padded/transposed bf16 x-tile in LDS
//    (xt[6][66][64], 50.7 KB) with an XOR swizzle (byte ^= (wc&7)<<4) so the
//    MFMA-phase ds_read_b128 (stride-128B column reads, otherwise 16-way
//    bank conflict) is ~2-way max.
//  - A-fragments now load straight from L2-resident Wpack (589 KB, hot in
//    every XCD L2) instead of being staged in ldsA: frees 48 KB LDS and
//    removes ALL K-loop barriers (the per-r vmcnt(0)+s_barrier drain was the
//    structural stall; body is now a straight 576-MFMA stream the compiler
//    can pipeline).
//  - Prep is now wpack-only (72 blocks, ~1 MB traffic, ~2 us).
// Cost: x re-read ~1.5x (row overlap between adjacent h0 quads) = +26 MB HBM,
// vs -58 MB xT traffic and -1 fat kernel.
// Predicted: main FETCH 27->~60-75 MB, MfmaUtil 21->~30%, total 162->~105 us.

#define BB 64
#define CC 64
#define COO 64
#define HH 56
#define WW 56

typedef __bf16 bf16x8 __attribute__((ext_vector_type(8)));
typedef float  f32x4  __attribute__((ext_vector_type(4)));

// ---- prep: weight pack only (verified R3+ body) ----------------------------
// Wpack[e*36864 + rs*4096 + ks*2048 + mt*512 + lane*8 + j]
//   = bf16( Wexp[e][mt*16+(lane&15)][ks*32+(lane>>4)*8+j][r][s] )
__global__ __launch_bounds__(256) void wpack_kernel(
    const float* __restrict__ Wexp, __bf16* __restrict__ Wpack)
{
    const int wp  = blockIdx.x;          // 0..71
    const int tid = threadIdx.x;
    const int e  = wp / 9, rs = wp - e * 9;
    const int r  = rs / 3, s  = rs - r * 3;
    for (int idx = tid; idx < 4096; idx += 256) {
        const int ks   = idx >> 11;
        const int rem  = idx & 2047;
        const int mt   = rem >> 9;
        const int lane = (rem >> 3) & 63;
        const int j    = idx & 7;
        const int co = mt * 16 + (lane & 15);
        const int c  = ks * 32 + ((lane >> 4) << 3) + j;
        const float v = Wexp[((((size_t)e * COO + co) * CC + c) * 3 + r) * 3 + s];
        Wpack[(size_t)e * 36864 + (size_t)rs * 4096 + idx] = (__bf16)v;
    }
}

// ---- Fused main: in-block transpose + barrier-free MFMA K-loop -------------
__global__ __launch_bounds__(256, 2) void moe_conv_fused(
    const float* __restrict__ x, const __bf16* __restrict__ Wpack,
    const float* __restrict__ gate_w, const int* __restrict__ gate_i,
    const float* __restrict__ bexp, float* __restrict__ out)
{
    // xt[lr][wc][c], bf16, XOR-swizzled within each 128B (lr,wc) row:
    //   element c lives at byte (lr*66+wc)*128 + ((2*c) ^ ((wc&7)<<4))
    __shared__ __align__(16) __bf16 xt[6 * 66 * CC];   // 50,688 B

    const int b   = blockIdx.y;
    const int h0  = blockIdx.x * 4;     // output rows h0..h0+3
    const int tid = threadIdx.x;
    const int wid = tid >> 6, lane = tid & 63;
    const int n15 = lane & 15, quad = lane >> 4;
    const int wcol = wid * 16 + n15;    // padded col 0..63

    // Phase 0: zero the whole tile (covers pad rows/cols).
    {
        bf16x8 z = {};
        for (int i = tid; i < 6 * 66 * CC / 8; i += 256)
            *(bf16x8*)(xt + i * 8) = z;
    }
    __syncthreads();

    // Phase 1: transpose-fill interior. Thread = (c = tid&63, tg = tid>>6).
    // Wave lanes span all 64 c at fixed (lr,wq): banks = permuted c>>1,
    // 2 lanes/bank (free).
    {
        const int c  = tid & 63;
        const int tg = tid >> 6;
        const float* xb = x + ((size_t)b * CC + c) * (HH * WW);
        char* xtb = (char*)xt;
        #pragma unroll
        for (int lr = 0; lr < 6; ++lr) {
            const int h = h0 + lr - 1;          // real input row
            if (h < 0 || h >= HH) continue;     // uniform per block
            for (int wq = tg; wq < 14; wq += 4) {
                const float4 f = *(const float4*)(xb + (size_t)h * WW + wq * 4);
                const float fv[4] = {f.x, f.y, f.z, f.w};
                #pragma unroll
                for (int u = 0; u < 4; ++u) {
                    const int wc = wq * 4 + u + 1;       // padded col 1..56
                    const int byte = (lr * 66 + wc) * 128 +
                                     ((c * 2) ^ ((wc & 7) << 4));
                    *(__bf16*)(xtb + byte) = (__bf16)fv[u];
                }
            }
        }
    }
    __syncthreads();

    const int   e0 = gate_i[b * 2 + 0], e1 = gate_i[b * 2 + 1];
    const float g0 = gate_w[b * 2 + 0], g1 = gate_w[b * 2 + 1];
    const __bf16* w0 = Wpack + (size_t)e0 * 36864;
    const __bf16* w1 = Wpack + (size_t)e1 * 36864;

    f32x4 acc[2][4][4] = {};            // [slot][mt][row t]

    // Barrier-free K-loop: 18 steps x (4 ds_read_b128 + 8 hot global 16B
    // + 32 MFMA), fully unrolled.
    #pragma unroll
    for (int r = 0; r < 3; ++r) {
        #pragma unroll
        for (int s = 0; s < 3; ++s) {
            const int wc1 = wcol + s;            // padded col 0..65
            const int sw  = (wc1 & 7) << 4;
            #pragma unroll
            for (int ks = 0; ks < 2; ++ks) {
                bf16x8 bf[4];
                #pragma unroll
                for (int t = 0; t < 4; ++t) {
                    const int lr = t + r;        // padded row - h0, 0..5
                    const int byte = (lr * 66 + wc1) * 128 +
                                     ((ks * 64 + quad * 16) ^ sw);
                    bf[t] = *(const bf16x8*)((const char*)xt + byte);
                }
                const size_t rsks = (size_t)(r * 3 + s) * 4096 + ks * 2048;
                #pragma unroll
                for (int slot = 0; slot < 2; ++slot) {
                    const __bf16* wp = (slot ? w1 : w0) + rsks + lane * 8;
                    #pragma unroll
                    for (int mt = 0; mt < 4; ++mt) {
                        const bf16x8 af = *(const bf16x8*)(wp + mt * 512);
                        #pragma unroll
                        for (int t = 0; t < 4; ++t)
                            acc[slot][mt][t] = __builtin_amdgcn_mfma_f32_16x16x32_bf16(
                                af, bf[t], acc[slot][mt][t], 0, 0, 0);
                    }
                }
            }
        }
    }

    // Epilogue: D layout col=lane&15 (pixel), row=quad*4+reg (co within mt)
    if (wcol < WW) {
        #pragma unroll
        for (int t = 0; t < 4; ++t) {
            const int h = h0 + t;
            #pragma unroll
            for (int mt = 0; mt < 4; ++mt) {
                #pragma unroll
                for (int v = 0; v < 4; ++v) {
                    const int co = mt * 16 + quad * 4 + v;
                    float a0 = acc[0][mt][t][v] + bexp[e0 * COO + co];
                    float a1 = acc[1][mt][t][v] + bexp[e1 * COO + co];
                    a0 = fmaxf(a0, 0.f);
                    a1 = fmaxf(a1, 0.f);
                    out[(((size_t)b * COO + co) * HH + h) * WW + wcol] =
                        g0 * a0 + g1 * a1;
                }
            }
        }
    }
}

extern "C" void kernel_launch(void* const* d_in, const int* in_sizes, int n_in,
                              void* d_out, int out_size, void* d_ws, size_t ws_size,
                              hipStream_t stream) {
    const float* x      = (const float*)d_in[0];
    const float* gate_w = (const float*)d_in[1];
    const int*   gate_i = (const int*)  d_in[2];
    const float* Wexp   = (const float*)d_in[3];
    const float* bexp   = (const float*)d_in[4];
    float* out = (float*)d_out;

    __bf16* Wpack = (__bf16*)d_ws;      // 589,824 B

    wpack_kernel<<<dim3(72), 256, 0, stream>>>(Wexp, Wpack);
    moe_conv_fused<<<dim3(14, BB), 256, 0, stream>>>(x, Wpack, gate_w, gate_i,
                                                     bexp, out);
}

// Round 3
// 147.573 us; speedup vs baseline: 1.2495x; 1.2495x over previous
//
#include <hip/hip_runtime.h>

// MoE top-2 of 3x3 SAME convs via bf16 MFMA implicit GEMM.
//
// R9 = R8 resubmit (R8's bench died with "container failed twice" — no
// compile error, no timing block; R7 already showed acquire_s degrading
// 6.4->59s. Full audit found no hang/fault path: uniform barriers, all
// bounds in range, bijective swizzle, m97-pattern global_load_lds).
//
// R8 theory: main is occupancy/latency-bound (all pipes <=21%).
//  - CO split across blocks (mh): 2 mt per block -> acc 64 regs (was 128).
//    grid -> 1792 flat blocks; __launch_bounds__(256,4) targets
//    4 blocks/CU = 16 waves/CU (was ~8).
//  - A-staging per (r,s): 8KB/stage, double-buffered (16KB LDS, was 48KB),
//    via global_load_lds width=16 (no staging VGPRs, no ds_write; stage(rs+1)
//    issued right after barrier flies across compute(rs)).
//  - XCD swizzle (1792%8==0, bijective): 224 consecutive swz per XCD = 4
//    samples' xT (2MB) + Wpack (0.6MB) L2-resident -> absorbs the 2x xT
//    re-read the CO-split causes.
//  - xT layout [b][hp 58][cg 8][wc 66][8]: B-frag wave-load = 4x256B segments.
// Predicted: main 59 -> ~35-42us, Occ 16->40%, Mfma 21->33%, WRITE flat
// at ~51MB (rise = spills), total ~140us.

#define BB 64
#define CC 64
#define COO 64
#define HH 56
#define WW 56

typedef __bf16 bf16x8 __attribute__((ext_vector_type(8)));
typedef float  f32x4  __attribute__((ext_vector_type(4)));

// ---- prep: fused transpose (fat blocks) + weight pack ----------------------
__global__ __launch_bounds__(256) void prep_kernel(
    const float* __restrict__ x, const float* __restrict__ Wexp,
    __bf16* __restrict__ xT, __bf16* __restrict__ Wpack)
{
    const int bx  = blockIdx.x;
    const int tid = threadIdx.x;

    if (bx < 960) {
        // ---- xpose part: 4 hp-rows per block -------------------------------
        // Output row layout: [cg 8][wc 66][8 c] (c-octet-major), 4224 bf16/row.
        __shared__ float tile[CC][WW + 1];   // stride 57: reads 2-way max
        const int b   = bx / 15;
        const int grp = bx - b * 15;         // 0..14 -> hp = grp*4 + rr
        #pragma unroll 1
        for (int rr = 0; rr < 4; ++rr) {
            const int hp = grp * 4 + rr;
            if (hp >= 58) break;
            __bf16* dst = xT + ((size_t)b * 58 + hp) * 4224;
            const bool interior = (hp >= 1 && hp <= HH);
            if (!interior) {                 // pad row: zero-fill (no LDS use)
                bf16x8 z = {};
                for (int j = tid; j < 4224 / 8; j += 256)
                    *(bf16x8*)(dst + j * 8) = z;
                continue;                    // hp uniform per block: no diverge
            }
            const int h = hp - 1;
            const float* xb = x + (size_t)b * CC * HH * WW + (size_t)h * WW;
            for (int i = tid; i < CC * 14; i += 256) {
                const int c = i / 14, wq = i - c * 14;
                const float4 f = *(const float4*)(xb + (size_t)c * HH * WW + wq * 4);
                tile[c][wq * 4 + 0] = f.x; tile[c][wq * 4 + 1] = f.y;
                tile[c][wq * 4 + 2] = f.z; tile[c][wq * 4 + 3] = f.w;
            }
            __syncthreads();
            for (int j = tid; j < 66 * 8; j += 256) {
                const int cg = j / 66;           // c-octet 0..7
                const int wc = j - cg * 66;      // padded col 0..65
                bf16x8 v = {};
                if (wc >= 1 && wc <= WW) {
                    const int w = wc - 1;
                    #pragma unroll
                    for (int u = 0; u < 8; ++u)
                        v[u] = (__bf16)tile[cg * 8 + u][w];
                }
                *(bf16x8*)(dst + j * 8) = v;     // 16B coalesced (j-linear)
            }
            __syncthreads();                 // before next rr reuses tile
        }
    } else {
        // ---- wpack part (verified R3+ body) --------------------------------
        // Wpack[e*36864 + rs*4096 + ks*2048 + mt*512 + lane*8 + j]
        //   = bf16( Wexp[e][mt*16+(lane&15)][ks*32+(lane>>4)*8+j][r][s] )
        const int wp = bx - 960;             // 0..71
        const int e  = wp / 9, rs = wp - e * 9;
        const int r  = rs / 3, s  = rs - r * 3;
        for (int idx = tid; idx < 4096; idx += 256) {
            const int ks   = idx >> 11;
            const int rem  = idx & 2047;
            const int mt   = rem >> 9;
            const int lane = (rem >> 3) & 63;
            const int j    = idx & 7;
            const int co = mt * 16 + (lane & 15);
            const int c  = ks * 32 + ((lane >> 4) << 3) + j;
            const float v = Wexp[((((size_t)e * COO + co) * CC + c) * 3 + r) * 3 + s];
            Wpack[(size_t)e * 36864 + (size_t)rs * 4096 + idx] = (__bf16)v;
        }
    }
}

// ---- Main: MFMA implicit GEMM, CO-split blocks, dbuf (r,s) staging ---------
__global__ __launch_bounds__(256, 4) void moe_conv_mfma(
    const __bf16* __restrict__ xT, const __bf16* __restrict__ Wpack,
    const float* __restrict__ gate_w, const int* __restrict__ gate_i,
    const float* __restrict__ bexp, float* __restrict__ out)
{
    __shared__ __align__(16) __bf16 ldsA[2 * 4096];  // 2 bufs x 8KB = 16KB

    // XCD swizzle: 1792 blocks, 224 consecutive swz per XCD (= 4 samples).
    const int bid = blockIdx.x;
    const int swz = (bid & 7) * 224 + (bid >> 3);
    const int b   = swz / 28;
    const int rem = swz - b * 28;
    const int h0  = (rem >> 1) * 4;     // output rows h0..h0+3
    const int mh  = rem & 1;            // CO half: mt = mh*2 + mtl

    const int tid = threadIdx.x;
    const int wid = tid >> 6, lane = tid & 63;
    const int n15 = lane & 15, quad = lane >> 4;
    const int wcol = wid * 16 + n15;    // padded col 0..63

    const int   e0 = gate_i[b * 2 + 0], e1 = gate_i[b * 2 + 1];
    const float g0 = gate_w[b * 2 + 0], g1 = gate_w[b * 2 + 1];
    const __bf16* w0 = Wpack + (size_t)e0 * 36864;
    const __bf16* w1 = Wpack + (size_t)e1 * 36864;

    // Stage 8KB for step rs into buf: 8 chunks of 1KB; wave wid does
    // chunk cid = wid*2+i = slot*4 + ks*2 + mtl with slot=(wid>=2), ks=wid&1,
    // mtl=i. LDS dest is wave-uniform base + lane*16B (global_load_lds rule).
    auto stage = [&](int rsn, int bufn) {
        #pragma unroll
        for (int i = 0; i < 2; ++i) {
            const __bf16* src = (wid >= 2 ? w1 : w0) + (size_t)rsn * 4096
                              + (wid & 1) * 2048 + (mh * 2 + i) * 512 + lane * 8;
            __bf16* dstp = &ldsA[bufn * 4096 + (wid * 2 + i) * 512 + lane * 8];
            __builtin_amdgcn_global_load_lds(
                (const __attribute__((address_space(1))) unsigned int*)src,
                (__attribute__((address_space(3))) unsigned int*)dstp, 16, 0, 0);
        }
    };

    // xT strides (bf16): b 244992, hp 4224, cg 528 (cg = ks*4 + quad).
    const __bf16* pq = xT + (size_t)b * 244992 + quad * 528 + wcol * 8;

    f32x4 acc[2][2][4] = {};            // [slot][mtl][row t]

    stage(0, 0);
    int r = 0, s = 0;
    #pragma unroll 1
    for (int rs = 0; rs < 9; ++rs) {
        const int buf = rs & 1;
        __syncthreads();                // stage(rs) landed; buf^1 readers done
        if (rs < 8) stage(rs + 1, buf ^ 1);

        const __bf16* pb = pq + (size_t)(h0 + r) * 4224 + s * 8;
        #pragma unroll
        for (int ks = 0; ks < 2; ++ks) {
            bf16x8 bf[4];
            #pragma unroll
            for (int t = 0; t < 4; ++t)
                bf[t] = *(const bf16x8*)(pb + t * 4224 + ks * 2112);
            #pragma unroll
            for (int slot = 0; slot < 2; ++slot) {
                #pragma unroll
                for (int mtl = 0; mtl < 2; ++mtl) {
                    const bf16x8 af = *(const bf16x8*)
                        &ldsA[buf * 4096 + slot * 2048 + ks * 1024 + mtl * 512 + lane * 8];
                    #pragma unroll
                    for (int t = 0; t < 4; ++t)
                        acc[slot][mtl][t] = __builtin_amdgcn_mfma_f32_16x16x32_bf16(
                            af, bf[t], acc[slot][mtl][t], 0, 0, 0);
                }
            }
        }
        if (++s == 3) { s = 0; ++r; }
    }

    // Epilogue: D layout col=lane&15 (pixel), row=quad*4+reg (co within mt)
    if (wcol < WW) {
        #pragma unroll
        for (int t = 0; t < 4; ++t) {
            const int h = h0 + t;
            #pragma unroll
            for (int mtl = 0; mtl < 2; ++mtl) {
                #pragma unroll
                for (int v = 0; v < 4; ++v) {
                    const int co = (mh * 2 + mtl) * 16 + quad * 4 + v;
                    float a0 = acc[0][mtl][t][v] + bexp[e0 * COO + co];
                    float a1 = acc[1][mtl][t][v] + bexp[e1 * COO + co];
                    a0 = fmaxf(a0, 0.f);
                    a1 = fmaxf(a1, 0.f);
                    out[(((size_t)b * COO + co) * HH + h) * WW + wcol] =
                        g0 * a0 + g1 * a1;
                }
            }
        }
    }
}

extern "C" void kernel_launch(void* const* d_in, const int* in_sizes, int n_in,
                              void* d_out, int out_size, void* d_ws, size_t ws_size,
                              hipStream_t stream) {
    const float* x      = (const float*)d_in[0];
    const float* gate_w = (const float*)d_in[1];
    const int*   gate_i = (const int*)  d_in[2];
    const float* Wexp   = (const float*)d_in[3];
    const float* bexp   = (const float*)d_in[4];
    float* out = (float*)d_out;

    // Wpack first (fixed 589,824 B, 16B-aligned), then xT (31,358,976 B).
    __bf16* Wpack = (__bf16*)d_ws;
    __bf16* xT    = (__bf16*)((char*)d_ws + 589824);

    prep_kernel<<<dim3(1032), 256, 0, stream>>>(x, Wexp, xT, Wpack);
    moe_conv_mfma<<<dim3(1792), 256, 0, stream>>>(xT, Wpack, gate_w, gate_i,
                                                  bexp, out);
}

// Round 4
// 146.293 us; speedup vs baseline: 1.2604x; 1.0088x over previous
//
#include <hip/hip_runtime.h>

// MoE top-2 of 3x3 SAME convs via bf16 MFMA implicit GEMM.
//
// R10 = R9 + register double-buffered B-fragment prefetch.
// R9 post-mortem: main 47us, real MFMA-pipe busy ~9% (2.06M MFMA = 10.1k
// cy/SIMD vs 112.8k elapsed). A-path is covered (LDS staged 1 step ahead),
// but B-frags (xT, L2-hot) were loaded and consumed inside the same step:
// ~200-400cy L2 latency on the critical path of every one of 9 steps, with
// only ~2.3 waves/SIMD to hide it.
// Fix: bfb[2][2][4] register dbuf; loads for step rs+1 issue right after the
// barrier of step rs (one full step of MFMA+ds_read cover before use; the
// compiler's vmcnt(0)@barrier then waits on covered loads, not fresh ones).
// rs-loop fully unrolled -> all bfb indices static (no scratch).
// Cost: +64 VGPR -> ~150; launch_bounds(256,3) (cap ~170, 3 blocks/CU).
// Predicted: main 47 -> ~30-35us, WRITE flat ~50MB (rise = spills), FETCH
// flat ~18.5MB, total ~128-134us.

#define BB 64
#define CC 64
#define COO 64
#define HH 56
#define WW 56

typedef __bf16 bf16x8 __attribute__((ext_vector_type(8)));
typedef float  f32x4  __attribute__((ext_vector_type(4)));

// ---- prep: fused transpose (fat blocks) + weight pack ----------------------
__global__ __launch_bounds__(256) void prep_kernel(
    const float* __restrict__ x, const float* __restrict__ Wexp,
    __bf16* __restrict__ xT, __bf16* __restrict__ Wpack)
{
    const int bx  = blockIdx.x;
    const int tid = threadIdx.x;

    if (bx < 960) {
        // ---- xpose part: 4 hp-rows per block -------------------------------
        // Output row layout: [cg 8][wc 66][8 c] (c-octet-major), 4224 bf16/row.
        __shared__ float tile[CC][WW + 1];   // stride 57: reads 2-way max
        const int b   = bx / 15;
        const int grp = bx - b * 15;         // 0..14 -> hp = grp*4 + rr
        #pragma unroll 1
        for (int rr = 0; rr < 4; ++rr) {
            const int hp = grp * 4 + rr;
            if (hp >= 58) break;
            __bf16* dst = xT + ((size_t)b * 58 + hp) * 4224;
            const bool interior = (hp >= 1 && hp <= HH);
            if (!interior) {                 // pad row: zero-fill (no LDS use)
                bf16x8 z = {};
                for (int j = tid; j < 4224 / 8; j += 256)
                    *(bf16x8*)(dst + j * 8) = z;
                continue;                    // hp uniform per block: no diverge
            }
            const int h = hp - 1;
            const float* xb = x + (size_t)b * CC * HH * WW + (size_t)h * WW;
            for (int i = tid; i < CC * 14; i += 256) {
                const int c = i / 14, wq = i - c * 14;
                const float4 f = *(const float4*)(xb + (size_t)c * HH * WW + wq * 4);
                tile[c][wq * 4 + 0] = f.x; tile[c][wq * 4 + 1] = f.y;
                tile[c][wq * 4 + 2] = f.z; tile[c][wq * 4 + 3] = f.w;
            }
            __syncthreads();
            for (int j = tid; j < 66 * 8; j += 256) {
                const int cg = j / 66;           // c-octet 0..7
                const int wc = j - cg * 66;      // padded col 0..65
                bf16x8 v = {};
                if (wc >= 1 && wc <= WW) {
                    const int w = wc - 1;
                    #pragma unroll
                    for (int u = 0; u < 8; ++u)
                        v[u] = (__bf16)tile[cg * 8 + u][w];
                }
                *(bf16x8*)(dst + j * 8) = v;     // 16B coalesced (j-linear)
            }
            __syncthreads();                 // before next rr reuses tile
        }
    } else {
        // ---- wpack part (verified R3+ body) --------------------------------
        // Wpack[e*36864 + rs*4096 + ks*2048 + mt*512 + lane*8 + j]
        //   = bf16( Wexp[e][mt*16+(lane&15)][ks*32+(lane>>4)*8+j][r][s] )
        const int wp = bx - 960;             // 0..71
        const int e  = wp / 9, rs = wp - e * 9;
        const int r  = rs / 3, s  = rs - r * 3;
        for (int idx = tid; idx < 4096; idx += 256) {
            const int ks   = idx >> 11;
            const int rem  = idx & 2047;
            const int mt   = rem >> 9;
            const int lane = (rem >> 3) & 63;
            const int j    = idx & 7;
            const int co = mt * 16 + (lane & 15);
            const int c  = ks * 32 + ((lane >> 4) << 3) + j;
            const float v = Wexp[((((size_t)e * COO + co) * CC + c) * 3 + r) * 3 + s];
            Wpack[(size_t)e * 36864 + (size_t)rs * 4096 + idx] = (__bf16)v;
        }
    }
}

// ---- Main: MFMA implicit GEMM, CO-split, dbuf LDS A + dbuf reg B -----------
__global__ __launch_bounds__(256, 3) void moe_conv_mfma(
    const __bf16* __restrict__ xT, const __bf16* __restrict__ Wpack,
    const float* __restrict__ gate_w, const int* __restrict__ gate_i,
    const float* __restrict__ bexp, float* __restrict__ out)
{
    __shared__ __align__(16) __bf16 ldsA[2 * 4096];  // 2 bufs x 8KB = 16KB

    // XCD swizzle: 1792 blocks, 224 consecutive swz per XCD (= 4 samples).
    const int bid = blockIdx.x;
    const int swz = (bid & 7) * 224 + (bid >> 3);
    const int b   = swz / 28;
    const int rem = swz - b * 28;
    const int h0  = (rem >> 1) * 4;     // output rows h0..h0+3
    const int mh  = rem & 1;            // CO half: mt = mh*2 + mtl

    const int tid = threadIdx.x;
    const int wid = tid >> 6, lane = tid & 63;
    const int n15 = lane & 15, quad = lane >> 4;
    const int wcol = wid * 16 + n15;    // padded col 0..63

    const int   e0 = gate_i[b * 2 + 0], e1 = gate_i[b * 2 + 1];
    const float g0 = gate_w[b * 2 + 0], g1 = gate_w[b * 2 + 1];
    const __bf16* w0 = Wpack + (size_t)e0 * 36864;
    const __bf16* w1 = Wpack + (size_t)e1 * 36864;

    // Stage 8KB for step rs into buf: 8 chunks of 1KB; wave wid does
    // chunk cid = wid*2+i = slot*4 + ks*2 + mtl with slot=(wid>=2), ks=wid&1,
    // mtl=i. LDS dest is wave-uniform base + lane*16B (global_load_lds rule).
    auto stage = [&](int rsn, int bufn) {
        #pragma unroll
        for (int i = 0; i < 2; ++i) {
            const __bf16* src = (wid >= 2 ? w1 : w0) + (size_t)rsn * 4096
                              + (wid & 1) * 2048 + (mh * 2 + i) * 512 + lane * 8;
            __bf16* dstp = &ldsA[bufn * 4096 + (wid * 2 + i) * 512 + lane * 8];
            __builtin_amdgcn_global_load_lds(
                (const __attribute__((address_space(1))) unsigned int*)src,
                (__attribute__((address_space(3))) unsigned int*)dstp, 16, 0, 0);
        }
    };

    // xT strides (bf16): b 244992, hp 4224, cg 528 (cg = ks*4 + quad).
    const __bf16* pq = xT + (size_t)b * 244992 + quad * 528 + wcol * 8;

    f32x4  acc[2][2][4] = {};           // [slot][mtl][row t]
    bf16x8 bfb[2][2][4];                // reg dbuf: [pf][ks][row t]

    // Load B-frags for step rsn into bfb[pf] (static indices after unroll).
    auto loadB = [&](int rsn, int pf) {
        const int rn = rsn / 3, sn = rsn - rn * 3;
        const __bf16* pb = pq + (size_t)(h0 + rn) * 4224 + sn * 8;
        #pragma unroll
        for (int ks = 0; ks < 2; ++ks)
            #pragma unroll
            for (int t = 0; t < 4; ++t)
                bfb[pf][ks][t] = *(const bf16x8*)(pb + t * 4224 + ks * 2112);
    };

    stage(0, 0);
    loadB(0, 0);
    #pragma unroll
    for (int rs = 0; rs < 9; ++rs) {
        const int buf = rs & 1;
        __syncthreads();                // stage(rs) landed; buf^1 readers done
        if (rs < 8) {
            stage(rs + 1, buf ^ 1);     // A for rs+1 -> other LDS buf
            loadB(rs + 1, buf ^ 1);     // B for rs+1 -> other reg buf
        }
        #pragma unroll
        for (int ks = 0; ks < 2; ++ks) {
            #pragma unroll
            for (int slot = 0; slot < 2; ++slot) {
                #pragma unroll
                for (int mtl = 0; mtl < 2; ++mtl) {
                    const bf16x8 af = *(const bf16x8*)
                        &ldsA[buf * 4096 + slot * 2048 + ks * 1024 + mtl * 512 + lane * 8];
                    #pragma unroll
                    for (int t = 0; t < 4; ++t)
                        acc[slot][mtl][t] = __builtin_amdgcn_mfma_f32_16x16x32_bf16(
                            af, bfb[buf][ks][t], acc[slot][mtl][t], 0, 0, 0);
                }
            }
        }
    }

    // Epilogue: D layout col=lane&15 (pixel), row=quad*4+reg (co within mt)
    if (wcol < WW) {
        #pragma unroll
        for (int t = 0; t < 4; ++t) {
            const int h = h0 + t;
            #pragma unroll
            for (int mtl = 0; mtl < 2; ++mtl) {
                #pragma unroll
                for (int v = 0; v < 4; ++v) {
                    const int co = (mh * 2 + mtl) * 16 + quad * 4 + v;
                    float a0 = acc[0][mtl][t][v] + bexp[e0 * COO + co];
                    float a1 = acc[1][mtl][t][v] + bexp[e1 * COO + co];
                    a0 = fmaxf(a0, 0.f);
                    a1 = fmaxf(a1, 0.f);
                    out[(((size_t)b * COO + co) * HH + h) * WW + wcol] =
                        g0 * a0 + g1 * a1;
                }
            }
        }
    }
}

extern "C" void kernel_launch(void* const* d_in, const int* in_sizes, int n_in,
                              void* d_out, int out_size, void* d_ws, size_t ws_size,
                              hipStream_t stream) {
    const float* x      = (const float*)d_in[0];
    const float* gate_w = (const float*)d_in[1];
    const int*   gate_i = (const int*)  d_in[2];
    const float* Wexp   = (const float*)d_in[3];
    const float* bexp   = (const float*)d_in[4];
    float* out = (float*)d_out;

    // Wpack first (fixed 589,824 B, 16B-aligned), then xT (31,358,976 B).
    __bf16* Wpack = (__bf16*)d_ws;
    __bf16* xT    = (__bf16*)((char*)d_ws + 589824);

    prep_kernel<<<dim3(1032), 256, 0, stream>>>(x, Wexp, xT, Wpack);
    moe_conv_mfma<<<dim3(1792), 256, 0, stream>>>(xT, Wpack, gate_w, gate_i,
                                                  bexp, out);
}